// Round 4
// baseline (59.331 us; speedup 1.0000x reference)
//
#include <hip/hip_runtime.h>

#define HOP       256
#define WD        32
#define NSTEP     416          // (FRAMELEN - FILTERLEN) - WD
#define NFRM      4096
#define TLEN      1048832      // FRAMELEN + HOP*(NFRM-1)
#define LROW      786688       // 448 + 4095*192
#define FPB       8            // frames per block
#define XW        2272         // 7*HOP + 480 staged x floats
#define XWP       2288         // + pad for last-group prefetch overrun
#define DW        2208         // staged d floats per batch
#define DWP       2244         // padded stride (mod 32 == 4)

// 16-lane butterfly sum within each row of 16; result in ALL lanes.
__device__ __forceinline__ float row_sum16(float v) {
    v += __int_as_float(__builtin_amdgcn_update_dpp(0, __float_as_int(v), 0xB1,  0xF, 0xF, true));
    v += __int_as_float(__builtin_amdgcn_update_dpp(0, __float_as_int(v), 0x4E,  0xF, 0xF, true));
    v += __int_as_float(__builtin_amdgcn_update_dpp(0, __float_as_int(v), 0x141, 0xF, 0xF, true));
    v += __int_as_float(__builtin_amdgcn_update_dpp(0, __float_as_int(v), 0x140, 0xF, 0xF, true));
    return v;
}

__device__ __forceinline__ float clampw(float v) {
    return fminf(fmaxf(v, -65535.0f), 65535.0f);
}

// One LMS step with register-resident x window + d value.
#define STEP(X0, X1, X2, X3, DV, J, STORE) do {                    \
    float p = w0 * (X0);                                           \
    p = fmaf(w1, (X1), p);                                         \
    p = fmaf(w2, (X2), p);                                         \
    p = fmaf(w3, (X3), p);                                         \
    float s = row_sum16(p);                                        \
    float e = (DV) - s;                                            \
    if (STORE) { so = (col == (J)) ? s : so;                       \
                 eo = (col == (J)) ? e : eo; }                     \
    float g = 0.05f * e;                                           \
    w0 = clampw(fmaf(g, (X0), w0));                                \
    w1 = clampw(fmaf(g, (X1), w1));                                \
    w2 = clampw(fmaf(g, (X2), w2));                                \
    w3 = clampw(fmaf(g, (X3), w3));                                \
} while (0)

#define GROUP(STORE) do {                                          \
    STEP(xa.x, xa.y, xa.z, xa.w, dv.x, 0, STORE);                  \
    STEP(xa.y, xa.z, xa.w, xb.x, dv.y, 1, STORE);                  \
    STEP(xa.z, xa.w, xb.x, xb.y, dv.z, 2, STORE);                  \
    STEP(xa.w, xb.x, xb.y, xb.z, dv.w, 3, STORE);                  \
} while (0)

// wave = 4 chains (rows of 16 lanes), 4 taps/lane. block = 16 chains.
__global__ void __launch_bounds__(256, 2)
lms_kernel(const float* __restrict__ dmat, const float* __restrict__ xvec,
           float* __restrict__ out)
{
    __shared__ __align__(16) float lx[XWP];
    __shared__ __align__(16) float ld[2][DWP];

    const int tid   = threadIdx.x;
    const int f_blk = blockIdx.x * FPB;
    const size_t xg = (size_t)f_blk * HOP;

    // ---- stage x and d via float4 ----
    {
        const float4* __restrict__ sx = (const float4*)(xvec + xg);
        float4* dx = (float4*)lx;
        #pragma unroll
        for (int i = 0; i < 3; ++i) {
            int k = tid + 256 * i;
            if (k < XW / 4) dx[k] = sx[k];
        }
        const float4* __restrict__ s0 = (const float4*)(dmat + xg + WD);
        const float4* __restrict__ s1 = (const float4*)(dmat + (size_t)TLEN + xg + WD);
        float4* d0 = (float4*)ld[0];
        float4* d1 = (float4*)ld[1];
        #pragma unroll
        for (int i = 0; i < 3; ++i) {
            int k = tid + 256 * i;
            if (k < DW / 4) { d0[k] = s0[k]; d1[k] = s1[k]; }
        }
    }
    __syncthreads();

    const int lane = tid & 63;
    const int wv   = tid >> 6;
    const int row  = lane >> 4;            // 0..3 within wave
    const int col  = lane & 15;            // tap group: taps 4c..4c+3
    const int fl   = 2 * wv + (row >> 1);  // local frame 0..7
    const int b    = row & 1;              // batch
    const int f    = f_blk + fl;           // global frame

    // per-lane base pointers, both 16B-aligned
    const float4* __restrict__ xq = (const float4*)(lx + fl * HOP + 4 * col);
    const float4* __restrict__ dq = (const float4*)(ld[b] + fl * HOP);

    float* od = out + (size_t)b * LROW + 32 + (size_t)192 * f;
    float* oe = od + 2 * (size_t)LROW;

    // leading 32 zeros of each of the 4 output rows
    if (f_blk == 0 && tid < 128) {
        out[(size_t)(tid >> 5) * LROW + (tid & 31)] = 0.0f;
    }

    float w0 = 0.f, w1 = 0.f, w2 = 0.f, w3 = 0.f;

    float4 xa = xq[0], xb = xq[1];
    float4 dv = dq[0];

    if (f == 0) {
        #pragma unroll 2
        for (int u = 0; u < 104; ++u) {
            float4 xn = xq[u + 2];      // prefetch next group's x
            float4 dn = dq[u + 1];      // prefetch next group's d
            float so = 0.f, eo = 0.f;
            GROUP(true);
            if (col < 4) { od[4 * u + col] = so; oe[4 * u + col] = eo; }
            xa = xb; xb = xn; dv = dn;
        }
    } else {
        #pragma unroll 2
        for (int u = 0; u < 56; ++u) {
            float4 xn = xq[u + 2];
            float4 dn = dq[u + 1];
            float so = 0.f, eo = 0.f;
            (void)so; (void)eo;
            GROUP(false);
            xa = xb; xb = xn; dv = dn;
        }
        #pragma unroll 2
        for (int u = 56; u < 104; ++u) {
            float4 xn = xq[u + 2];
            float4 dn = dq[u + 1];
            float so = 0.f, eo = 0.f;
            GROUP(true);
            if (col < 4) { od[4 * u + col] = so; oe[4 * u + col] = eo; }
            xa = xb; xb = xn; dv = dn;
        }
    }
}

extern "C" void kernel_launch(void* const* d_in, const int* in_sizes, int n_in,
                              void* d_out, int out_size, void* d_ws, size_t ws_size,
                              hipStream_t stream) {
    const float* dmat = (const float*)d_in[0];   // (2, TLEN)
    const float* xvec = (const float*)d_in[1];   // (TLEN,)
    float* out = (float*)d_out;                  // [d_est(2,LROW), e(2,LROW)]

    hipLaunchKernelGGL(lms_kernel, dim3(NFRM / FPB), dim3(256), 0, stream,
                       dmat, xvec, out);
}

// Round 5
// 51.017 us; speedup vs baseline: 1.1630x; 1.1630x over previous
//
#include <hip/hip_runtime.h>

#define HOP     256
#define WD      32
#define NSTEP   416            // (FRAMELEN - FILTERLEN) - WD
#define NFRM    4096
#define TLEN    1048832        // FRAMELEN + HOP*(NFRM-1)
#define LROW    786688         // 448 + 4095*192
#define FPB     8              // frames per block
#define XSTR    484            // padded x words per frame (484 % 32 == 4)
#define DSTR    420            // padded d words per chain (420 % 32 == 4)
#define XQ      121            // XSTR/4
#define DQ      105            // DSTR/4
#define XTOT    (FPB*XSTR + 16)      // + guard for dead prefetch overrun
#define DTOT    (2*FPB*DSTR + 8)

// 8-lane butterfly sum within each aligned group of 8 lanes; result in all 8.
__device__ __forceinline__ float red8(float v) {
    v += __int_as_float(__builtin_amdgcn_update_dpp(0, __float_as_int(v), 0xB1,  0xF, 0xF, true)); // xor1
    v += __int_as_float(__builtin_amdgcn_update_dpp(0, __float_as_int(v), 0x4E,  0xF, 0xF, true)); // xor2
    v += __int_as_float(__builtin_amdgcn_update_dpp(0, __float_as_int(v), 0x141, 0xF, 0xF, true)); // half-mirror
    return v;
}

#define CL(v) __builtin_amdgcn_fmed3f((v), -65535.0f, 65535.0f)

// One LMS step; 8 taps/lane, window floats X0..X7, desired DV, capture slot J.
#define STEP(X0,X1,X2,X3,X4,X5,X6,X7, DV, J) do {                 \
    float pA = w0 * (X0);                                         \
    pA = fmaf(w1, (X1), pA);                                      \
    pA = fmaf(w2, (X2), pA);                                      \
    pA = fmaf(w3, (X3), pA);                                      \
    float pB = w4 * (X4);                                         \
    pB = fmaf(w5, (X5), pB);                                      \
    pB = fmaf(w6, (X6), pB);                                      \
    pB = fmaf(w7, (X7), pB);                                      \
    float s  = red8(pA + pB);                                     \
    float e  = (DV) - s;                                          \
    so = (col == (J)) ? s : so;                                   \
    eo = (col == (J)) ? e : eo;                                   \
    float gm = 0.05f * e;                                         \
    w0 = CL(fmaf(gm, (X0), w0));                                  \
    w1 = CL(fmaf(gm, (X1), w1));                                  \
    w2 = CL(fmaf(gm, (X2), w2));                                  \
    w3 = CL(fmaf(gm, (X3), w3));                                  \
    w4 = CL(fmaf(gm, (X4), w4));                                  \
    w5 = CL(fmaf(gm, (X5), w5));                                  \
    w6 = CL(fmaf(gm, (X6), w6));                                  \
    w7 = CL(fmaf(gm, (X7), w7));                                  \
} while (0)

// 8 steps (one store-group) from 4 x-quads + 2 d-quads.
#define GROUP8(q0,q1,q2,q3, da,db) do {                           \
    STEP(q0.x,q0.y,q0.z,q0.w,q1.x,q1.y,q1.z,q1.w, da.x, 0);       \
    STEP(q0.y,q0.z,q0.w,q1.x,q1.y,q1.z,q1.w,q2.x, da.y, 1);       \
    STEP(q0.z,q0.w,q1.x,q1.y,q1.z,q1.w,q2.x,q2.y, da.z, 2);       \
    STEP(q0.w,q1.x,q1.y,q1.z,q1.w,q2.x,q2.y,q2.z, da.w, 3);       \
    STEP(q1.x,q1.y,q1.z,q1.w,q2.x,q2.y,q2.z,q2.w, db.x, 4);       \
    STEP(q1.y,q1.z,q1.w,q2.x,q2.y,q2.z,q2.w,q3.x, db.y, 5);       \
    STEP(q1.z,q1.w,q2.x,q2.y,q2.z,q2.w,q3.x,q3.y, db.z, 6);       \
    STEP(q1.w,q2.x,q2.y,q2.z,q2.w,q3.x,q3.y,q3.z, db.w, 7);       \
} while (0)

// block = 128 threads = 2 waves = 16 chains = 8 frames x 2 batches.
__global__ void __launch_bounds__(128, 1)
lms_kernel(const float* __restrict__ dmat, const float* __restrict__ xvec,
           float* __restrict__ out)
{
    __shared__ __align__(16) float lx[XTOT];   // per-frame x, padded stride
    __shared__ __align__(16) float ld[DTOT];   // per-(b,frame) d, padded stride

    const int tid = threadIdx.x;
    const int f0  = blockIdx.x * FPB;

    // ---- stage: 968 x-quads + 1680 d-quads; dst quad index == i ----
    for (int i = tid; i < 968 + 1680; i += 128) {
        if (i < 968) {
            int fr = i / XQ, k = i - fr * XQ;
            ((float4*)lx)[i] =
                *(const float4*)(xvec + (size_t)(f0 + fr) * HOP + 4 * k);
        } else {
            int j = i - 968;
            int idx = j / DQ, k = j - idx * DQ;   // idx = b*8 + r
            int b = idx >> 3, r = idx & 7;
            ((float4*)ld)[j] =
                *(const float4*)(dmat + (size_t)b * TLEN
                                 + (size_t)(f0 + r) * HOP + WD + 4 * k);
        }
    }
    __syncthreads();

    const int lane = tid & 63;
    const int wv   = tid >> 6;             // 0..1
    const int row  = lane >> 3;            // 0..7 (8-lane group)
    const int col  = lane & 7;             // taps 8*col .. 8*col+7
    const int fr   = 4 * wv + (row >> 1);  // local frame 0..7
    const int b    = row & 1;              // batch
    const int f    = f0 + fr;              // global frame
    const bool early = (f == 0);           // stores for t < 224?

    const float4* __restrict__ xq = (const float4*)(lx + fr * XSTR + 8 * col);
    const float4* __restrict__ dq = (const float4*)(ld + (b * FPB + fr) * DSTR);

    float* od = out + (size_t)b * LROW + 32 + (size_t)192 * f;
    float* oe = od + 2 * (size_t)LROW;

    // leading 32 zeros of the 4 output rows (d_est b0,b1 / e b0,b1)
    if (blockIdx.x == 0) {
        out[(size_t)(tid >> 5) * LROW + (tid & 31)] = 0.0f;
    }

    float w0 = 0.f, w1 = 0.f, w2 = 0.f, w3 = 0.f,
          w4 = 0.f, w5 = 0.f, w6 = 0.f, w7 = 0.f;

    // prologue: load group g=0 into A
    float4 ax0 = xq[0], ax1 = xq[1], ax2 = xq[2], ax3 = xq[3];
    float4 ad0 = dq[0], ad1 = dq[1];

    for (int i = 0; i < 26; ++i) {
        // issue loads for g = 2i+1 into B (covered by the 8 A-steps below)
        float4 bx0 = xq[4*i+2], bx1 = xq[4*i+3],
               bx2 = xq[4*i+4], bx3 = xq[4*i+5];
        float4 bd0 = dq[4*i+2], bd1 = dq[4*i+3];
        {
            float so = 0.f, eo = 0.f;
            GROUP8(ax0, ax1, ax2, ax3, ad0, ad1);
            int g = 2 * i;
            if (g >= 28 || early) { od[8*g + col] = so; oe[8*g + col] = eo; }
        }
        // issue loads for g = 2i+2 into A (dead-guarded at i==25)
        ax0 = xq[4*i+4]; ax1 = xq[4*i+5]; ax2 = xq[4*i+6]; ax3 = xq[4*i+7];
        ad0 = dq[4*i+4]; ad1 = dq[4*i+5];
        {
            float so = 0.f, eo = 0.f;
            GROUP8(bx0, bx1, bx2, bx3, bd0, bd1);
            int g = 2 * i + 1;
            if (g >= 28 || early) { od[8*g + col] = so; oe[8*g + col] = eo; }
        }
    }
}

extern "C" void kernel_launch(void* const* d_in, const int* in_sizes, int n_in,
                              void* d_out, int out_size, void* d_ws, size_t ws_size,
                              hipStream_t stream) {
    const float* dmat = (const float*)d_in[0];   // (2, TLEN)
    const float* xvec = (const float*)d_in[1];   // (TLEN,)
    float* out = (float*)d_out;                  // [d_est(2,LROW), e(2,LROW)]

    hipLaunchKernelGGL(lms_kernel, dim3(NFRM / FPB), dim3(128), 0, stream,
                       dmat, xvec, out);
}